// Round 11
// baseline (690.494 us; speedup 1.0000x reference)
//
#include <hip/hip_runtime.h>
#include <math.h>

#define PI_F 3.14159265358979323846f

static __device__ __forceinline__ float2 cmulf2(float2 a, float2 b) {
    return make_float2(a.x * b.x - a.y * b.y, a.x * b.y + a.y * b.x);
}

// ---------------------------------------------------------------------------
// K1: three GEMMs C_t = X_t @ W_t^T + b_t fused via blockIdx.z.
// R10 diagnosis: 8x8 micro-tile = 4 ds_read_b128 per 64 FMA -> LDS pipe
// oversubscribed 1.5x (VALUBusy 70%). This version: 16x8 micro-tile,
// tile 256x128, 256 threads -> 6 b128 per 128 FMA (ratio 1.125).
// Split-A row groups (ty*8, 128+ty*8): a-frag reads bank-conflict-free.
// As stride 260: staging writes 2-way (free). Grid (4,64,3)=768 = 3 blk/CU.
// ---------------------------------------------------------------------------
__global__ __launch_bounds__(256) void gemm3_nt_bias(
    const float* __restrict__ X0, const float* __restrict__ X1, const float* __restrict__ X2,
    const float* __restrict__ W0, const float* __restrict__ W1, const float* __restrict__ W2,
    const float* __restrict__ B0, const float* __restrict__ B1, const float* __restrict__ B2,
    float* __restrict__ O0, float* __restrict__ O1, float* __restrict__ O2)
{
    const float* A; const float* W; const float* bias; float* C;
    switch (blockIdx.z) {
        case 0:  A = X0; W = W0; bias = B0; C = O0; break;
        case 1:  A = X1; W = W1; bias = B1; C = O1; break;
        default: A = X2; W = W2; bias = B2; C = O2; break;
    }

    __shared__ float As[16][260];   // [k][m] 256 + 4 pad (2-way staging writes)
    __shared__ float Bs[16][132];   // [k][n] 128 + 4 pad

    const int tid = threadIdx.x;
    const int m0 = blockIdx.y * 256;
    const int n0 = blockIdx.x * 128;
    const int tx = tid & 15;        // cols {tx*4..+3} and {64+tx*4..+3}
    const int ty = tid >> 4;        // rows {ty*8..+7} and {128+ty*8..+7}
    const int lr = tid >> 2;        // 0..63 staging row
    const int lc = (tid & 3) << 2;  // 0,4,8,12 staging k-col

    float acc[16][8];
#pragma unroll
    for (int i = 0; i < 16; ++i)
#pragma unroll
        for (int j = 0; j < 8; ++j) acc[i][j] = 0.f;

    for (int k0 = 0; k0 < 512; k0 += 16) {
#pragma unroll
        for (int it = 0; it < 4; ++it) {
            const int r = lr + (it << 6);
            const float4 av = *reinterpret_cast<const float4*>(
                A + (size_t)(m0 + r) * 512 + k0 + lc);
            As[lc + 0][r] = av.x; As[lc + 1][r] = av.y;
            As[lc + 2][r] = av.z; As[lc + 3][r] = av.w;
        }
#pragma unroll
        for (int it = 0; it < 2; ++it) {
            const int r = lr + (it << 6);
            const float4 wv = *reinterpret_cast<const float4*>(
                W + (size_t)(n0 + r) * 512 + k0 + lc);
            Bs[lc + 0][r] = wv.x; Bs[lc + 1][r] = wv.y;
            Bs[lc + 2][r] = wv.z; Bs[lc + 3][r] = wv.w;
        }
        __syncthreads();
#pragma unroll
        for (int kk = 0; kk < 16; ++kk) {
            const float4 a0 = *reinterpret_cast<const float4*>(&As[kk][ty << 3]);
            const float4 a1 = *reinterpret_cast<const float4*>(&As[kk][(ty << 3) + 4]);
            const float4 a2 = *reinterpret_cast<const float4*>(&As[kk][128 + (ty << 3)]);
            const float4 a3 = *reinterpret_cast<const float4*>(&As[kk][128 + (ty << 3) + 4]);
            const float4 b0 = *reinterpret_cast<const float4*>(&Bs[kk][tx << 2]);
            const float4 b1 = *reinterpret_cast<const float4*>(&Bs[kk][64 + (tx << 2)]);
            const float a[16] = {a0.x, a0.y, a0.z, a0.w, a1.x, a1.y, a1.z, a1.w,
                                 a2.x, a2.y, a2.z, a2.w, a3.x, a3.y, a3.z, a3.w};
            const float b[8]  = {b0.x, b0.y, b0.z, b0.w, b1.x, b1.y, b1.z, b1.w};
#pragma unroll
            for (int i = 0; i < 16; ++i)
#pragma unroll
                for (int j = 0; j < 8; ++j)
                    acc[i][j] = fmaf(a[i], b[j], acc[i][j]);
        }
        __syncthreads();
    }

    const float4 bv0 = *reinterpret_cast<const float4*>(bias + n0 + (tx << 2));
    const float4 bv1 = *reinterpret_cast<const float4*>(bias + n0 + 64 + (tx << 2));
#pragma unroll
    for (int i = 0; i < 16; ++i) {
        const int r = m0 + ((i < 8) ? ((ty << 3) + i) : (128 + (ty << 3) + i - 8));
        float4 o0, o1;
        o0.x = acc[i][0] + bv0.x; o0.y = acc[i][1] + bv0.y;
        o0.z = acc[i][2] + bv0.z; o0.w = acc[i][3] + bv0.w;
        o1.x = acc[i][4] + bv1.x; o1.y = acc[i][5] + bv1.y;
        o1.z = acc[i][6] + bv1.z; o1.w = acc[i][7] + bv1.w;
        *reinterpret_cast<float4*>(C + (size_t)r * 512 + n0 + (tx << 2)) = o0;
        *reinterpret_cast<float4*>(C + (size_t)r * 512 + n0 + 64 + (tx << 2)) = o1;
    }
}

// ---------------------------------------------------------------------------
// K2: rfft-512 along L + top-4 mask for up to 3 tensors (blockIdx.y selects).
// Packed-real: 16 real cols -> 8 complex FFT-512, radix-8-grouped DIF
// (3 LDS round trips), conjugate-symmetry unpack, per-col top-4 threshold,
// masked write. dst layout: [b][f][d] float2.
// ---------------------------------------------------------------------------
__global__ __launch_bounds__(256) void fft3_topk_mask(
    const float* __restrict__ S0, const float* __restrict__ S1, const float* __restrict__ S2,
    float* __restrict__ D0, float* __restrict__ D1, float* __restrict__ D2)
{
    const float* src; float* dst;
    switch (blockIdx.y) {
        case 0:  src = S0; dst = D0; break;
        case 1:  src = S1; dst = D1; break;
        default: src = S2; dst = D2; break;
    }

    const int b  = blockIdx.x >> 5;
    const int dt = blockIdx.x & 31;
    const int tid = threadIdx.x;

    __shared__ float2 Zs[8][522];
    __shared__ float2 TW[256];
    __shared__ float4 red4[16][16];
    __shared__ float  thr2[16];

    {
        float sn, cs;
        sincosf(-PI_F * (float)tid * (1.0f / 256.0f), &sn, &cs);
        TW[tid] = make_float2(cs, sn);
    }

    {
        const int c  = tid & 7;
        const int l0 = tid >> 3;
        const float* p = src + (size_t)b * 262144 + dt * 16 + 2 * c;
#pragma unroll
        for (int it = 0; it < 16; ++it) {
            const int l = l0 + (it << 5);
            Zs[c][l] = *reinterpret_cast<const float2*>(p + (size_t)l * 512);
        }
    }
    __syncthreads();

#define BF(aa, bb, tt) { \
        const float2 s_ = make_float2(aa.x + bb.x, aa.y + bb.y); \
        const float2 d_ = make_float2(aa.x - bb.x, aa.y - bb.y); \
        aa = s_; bb = cmulf2(d_, tt); }

    {
        const int c  = tid & 7;
        const int g0 = tid >> 3;
#pragma unroll
        for (int grp = 0; grp < 3; ++grp) {
            const int s  = grp * 3;
            const int lg = 6 - s;
            const int bs = 512 >> s;
#pragma unroll
            for (int h = 0; h < 2; ++h) {
                const int g   = g0 + (h << 5);
                const int j   = g & ((1 << lg) - 1);
                const int blk = g >> lg;
                const int base = blk * bs + j;
                const int J   = j << s;

                float2 x0 = Zs[c][base];
                float2 x1 = Zs[c][base + (1 << lg)];
                float2 x2 = Zs[c][base + (2 << lg)];
                float2 x3 = Zs[c][base + (3 << lg)];
                float2 x4 = Zs[c][base + (4 << lg)];
                float2 x5 = Zs[c][base + (5 << lg)];
                float2 x6 = Zs[c][base + (6 << lg)];
                float2 x7 = Zs[c][base + (7 << lg)];

                const float2 tA0 = TW[J];
                const float2 tA1 = TW[J + 64];
                const float2 tA2 = TW[J + 128];
                const float2 tA3 = TW[J + 192];
                BF(x0, x4, tA0); BF(x1, x5, tA1);
                BF(x2, x6, tA2); BF(x3, x7, tA3);

                const float2 tB0 = TW[2 * J];
                const float2 tB1 = TW[2 * J + 128];
                BF(x0, x2, tB0); BF(x1, x3, tB1);
                BF(x4, x6, tB0); BF(x5, x7, tB1);

                const float2 tC = TW[4 * J];
                BF(x0, x1, tC); BF(x2, x3, tC);
                BF(x4, x5, tC); BF(x6, x7, tC);

                Zs[c][base]             = x0;
                Zs[c][base + (1 << lg)] = x1;
                Zs[c][base + (2 << lg)] = x2;
                Zs[c][base + (3 << lg)] = x3;
                Zs[c][base + (4 << lg)] = x4;
                Zs[c][base + (5 << lg)] = x5;
                Zs[c][base + (6 << lg)] = x6;
                Zs[c][base + (7 << lg)] = x7;
            }
            __syncthreads();
        }
    }
#undef BF

    {
        const int rc = tid & 15;
        const int fi = tid >> 4;
        const int cc = rc >> 1;
        const int part = rc & 1;
        float t0 = -1.f, t1 = -1.f, t2 = -1.f, t3 = -1.f;
        for (int f = fi; f <= 256; f += 16) {
            const int i1 = (int)(__brev((unsigned)f) >> 23);
            const int i2 = (int)(__brev((unsigned)((512 - f) & 511)) >> 23);
            const float2 z1 = Zs[cc][i1];
            const float2 z2 = Zs[cc][i2];
            float re, im;
            if (part == 0) { re = 0.5f * (z1.x + z2.x); im = 0.5f * (z1.y - z2.y); }
            else           { re = 0.5f * (z1.y + z2.y); im = 0.5f * (z2.x - z1.x); }
            const float a = re * re + im * im;
            if (a > t3) {
                if (a > t0)      { t3 = t2; t2 = t1; t1 = t0; t0 = a; }
                else if (a > t1) { t3 = t2; t2 = t1; t1 = a; }
                else if (a > t2) { t3 = t2; t2 = a; }
                else               t3 = a;
            }
        }
        red4[rc][fi] = make_float4(t0, t1, t2, t3);
        __syncthreads();
        if (tid < 16) {
            float m0 = -1.f, m1 = -1.f, m2 = -1.f, m3 = -1.f;
            for (int q2 = 0; q2 < 16; ++q2) {
                const float4 c4 = red4[tid][q2];
                const float vals[4] = {c4.x, c4.y, c4.z, c4.w};
#pragma unroll
                for (int q = 0; q < 4; ++q) {
                    const float a = vals[q];
                    if (a > m3) {
                        if (a > m0)      { m3 = m2; m2 = m1; m1 = m0; m0 = a; }
                        else if (a > m1) { m3 = m2; m2 = m1; m1 = a; }
                        else if (a > m2) { m3 = m2; m2 = a; }
                        else               m3 = a;
                    }
                }
            }
            thr2[tid] = m3;
        }
        __syncthreads();

        const float th = thr2[rc];
        float* outp = dst + ((size_t)b * (257 * 512) + (size_t)dt * 16 + rc) * 2;
        for (int f = fi; f <= 256; f += 16) {
            const int i1 = (int)(__brev((unsigned)f) >> 23);
            const int i2 = (int)(__brev((unsigned)((512 - f) & 511)) >> 23);
            const float2 z1 = Zs[cc][i1];
            const float2 z2 = Zs[cc][i2];
            float re, im;
            if (part == 0) { re = 0.5f * (z1.x + z2.x); im = 0.5f * (z1.y - z2.y); }
            else           { re = 0.5f * (z1.y + z2.y); im = 0.5f * (z2.x - z1.x); }
            const float a = re * re + im * im;
            const float2 o = (a >= th) ? make_float2(re, im) : make_float2(0.f, 0.f);
            *reinterpret_cast<float2*>(outp + (size_t)f * 1024) = o;
        }
    }
}

// ---------------------------------------------------------------------------
// K3: one wave per (b,f) row; 8 complex elems/thread (64B contiguous loads);
// softmax reductions via __shfl_xor butterfly — zero __syncthreads.
// ---------------------------------------------------------------------------
__global__ __launch_bounds__(64) void att_softmax_ctx(
    const float* __restrict__ qf,
    const float* __restrict__ kf,
    float* __restrict__ vf)
{
    const size_t row = (size_t)blockIdx.x * 1024;   // 512 complex
    const int tid = threadIdx.x;                    // 0..63

    const float4* q4 = reinterpret_cast<const float4*>(qf + row) + (tid << 2);
    const float4* k4 = reinterpret_cast<const float4*>(kf + row) + (tid << 2);
    float4*       v4 = reinterpret_cast<float4*>(vf + row) + (tid << 2);

    float re[8], im[8];
#pragma unroll
    for (int j = 0; j < 4; ++j) {
        const float4 q = q4[j];
        const float4 k = k4[j];
        re[2*j]   = q.x * k.x + q.y * k.y;
        im[2*j]   = q.y * k.x - q.x * k.y;
        re[2*j+1] = q.z * k.z + q.w * k.w;
        im[2*j+1] = q.w * k.z - q.z * k.w;
    }
    float mr = re[0], mi = im[0];
#pragma unroll
    for (int j = 1; j < 8; ++j) { mr = fmaxf(mr, re[j]); mi = fmaxf(mi, im[j]); }
#pragma unroll
    for (int o = 1; o < 64; o <<= 1) {
        mr = fmaxf(mr, __shfl_xor(mr, o, 64));
        mi = fmaxf(mi, __shfl_xor(mi, o, 64));
    }
    float er[8], ei[8];
    float sr = 0.f, si = 0.f;
#pragma unroll
    for (int j = 0; j < 8; ++j) {
        er[j] = expf(re[j] - mr); sr += er[j];
        ei[j] = expf(im[j] - mi); si += ei[j];
    }
#pragma unroll
    for (int o = 1; o < 64; o <<= 1) {
        sr += __shfl_xor(sr, o, 64);
        si += __shfl_xor(si, o, 64);
    }
    const float iSr = 1.0f / sr;
    const float iSi = 1.0f / si;
#pragma unroll
    for (int j = 0; j < 4; ++j) {
        const float4 v = v4[j];
        const float ar0 = er[2*j] * iSr,   ai0 = ei[2*j] * iSi;
        const float ar1 = er[2*j+1] * iSr, ai1 = ei[2*j+1] * iSi;
        float4 o;
        o.x = ar0 * v.x - ai0 * v.y;
        o.y = ar0 * v.y + ai0 * v.x;
        o.z = ar1 * v.z - ai1 * v.w;
        o.w = ar1 * v.w + ai1 * v.z;
        v4[j] = o;
    }
}

// ---------------------------------------------------------------------------
// K4: sparse inverse rDFT along f per (b,d) column + residual add.
// ---------------------------------------------------------------------------
__global__ __launch_bounds__(256) void irfft_residual(
    const float* __restrict__ ctx,    // [B][257][512] float2
    const float* __restrict__ query,  // [B][512][512]
    float* __restrict__ x)            // [B][512][512]
{
    const int b  = blockIdx.x >> 5;
    const int dt = blockIdx.x & 31;
    const int tid = threadIdx.x;

    __shared__ float2 Cs[16][259];
    __shared__ float2 Tt[512];

    for (int j = tid; j < 512; j += 256) {
        float sn, cs;
        sincosf(PI_F * (float)j * (1.0f / 256.0f), &sn, &cs);
        Tt[j] = make_float2(cs, sn);
    }
    {
        const int col = tid & 15;
        const int fr  = tid >> 4;
        const float* src = ctx + ((size_t)b * (257 * 512) + (size_t)dt * 16) * 2;
        for (int f = fr; f <= 256; f += 16) {
            Cs[col][f] = *reinterpret_cast<const float2*>(src + ((size_t)f * 512 + col) * 2);
        }
    }
    __syncthreads();

    const int col = tid & 15;
    const int w   = tid >> 4;
    float acc[32];
#pragma unroll
    for (int i = 0; i < 32; ++i) acc[i] = 0.f;

    for (int f = 0; f <= 256; ++f) {
        const float2 cv = Cs[col][f];
        if (cv.x != 0.f || cv.y != 0.f) {
            const float wgt = (f == 0 || f == 256) ? 1.f : 2.f;
            const float cr = cv.x * wgt, ci = cv.y * wgt;
            int idx = (f * w) & 511;
            const int stp = (f << 4) & 511;
#pragma unroll
            for (int i = 0; i < 32; ++i) {
                const float2 tw = Tt[idx];
                acc[i] = fmaf(cr, tw.x, fmaf(-ci, tw.y, acc[i]));
                idx = (idx + stp) & 511;
            }
        }
    }

    const float* qcol = query + (size_t)b * (512 * 512) + dt * 16 + col;
    float* xcol = x + (size_t)b * (512 * 512) + dt * 16 + col;
#pragma unroll
    for (int i = 0; i < 32; ++i) {
        const int l = w + (i << 4);
        xcol[(size_t)l * 512] = acc[i] * (1.0f / 512.0f) + qcol[(size_t)l * 512];
    }
}

// ---------------------------------------------------------------------------
// K5: LayerNorm along d.
// ---------------------------------------------------------------------------
__global__ __launch_bounds__(256) void layernorm_out(
    const float* __restrict__ x,
    const float* __restrict__ gamma,
    const float* __restrict__ beta,
    float* __restrict__ out)
{
    const int row = blockIdx.x;
    const float* xr = x + (size_t)row * 512;
    const int tid = threadIdx.x;
    __shared__ float sred[10];

    const float2 v = *reinterpret_cast<const float2*>(xr + tid * 2);
    float s = v.x + v.y;
    float q = v.x * v.x + v.y * v.y;
#pragma unroll
    for (int o = 32; o; o >>= 1) {
        s += __shfl_down(s, o, 64);
        q += __shfl_down(q, o, 64);
    }
    const int wid = tid >> 6, lane = tid & 63;
    if (lane == 0) { sred[wid] = s; sred[4 + wid] = q; }
    __syncthreads();
    if (tid == 0) {
        sred[8] = (sred[0] + sred[1]) + (sred[2] + sred[3]);
        sred[9] = (sred[4] + sred[5]) + (sred[6] + sred[7]);
    }
    __syncthreads();
    const float mean = sred[8] * (1.0f / 512.0f);
    const float var  = sred[9] * (1.0f / 512.0f) - mean * mean;
    const float rstd = 1.0f / sqrtf(var + 1e-5f);
    const float2 g  = *reinterpret_cast<const float2*>(gamma + tid * 2);
    const float2 be = *reinterpret_cast<const float2*>(beta + tid * 2);
    float2 o;
    o.x = (v.x - mean) * rstd * g.x + be.x;
    o.y = (v.y - mean) * rstd * g.y + be.y;
    *reinterpret_cast<float2*>(out + (size_t)row * 512 + tid * 2) = o;
}

// ---------------------------------------------------------------------------
extern "C" void kernel_launch(void* const* d_in, const int* in_sizes, int n_in,
                              void* d_out, int out_size, void* d_ws, size_t ws_size,
                              hipStream_t stream)
{
    const float* key   = (const float*)d_in[0];
    const float* value = (const float*)d_in[1];
    const float* query = (const float*)d_in[2];
    const float* Wk    = (const float*)d_in[3];
    const float* bk    = (const float*)d_in[4];
    const float* Wv    = (const float*)d_in[5];
    const float* bv    = (const float*)d_in[6];
    const float* Wq    = (const float*)d_in[7];
    const float* bq    = (const float*)d_in[8];
    const float* gamma = (const float*)d_in[9];
    const float* beta  = (const float*)d_in[10];
    float* out = (float*)d_out;

    float* ws = (float*)d_ws;
    const size_t TD = 8388608;   // 32*512*512 floats
    const size_t FQ = 8421376;   // 32*257*512*2 floats
    const size_t NEED_BYTES = (3 * TD + 3 * FQ) * sizeof(float);

    if (ws_size >= NEED_BYTES) {
        float* t0 = ws;
        float* t1 = ws + TD;
        float* t2 = ws + 2 * TD;
        float* f0 = ws + 3 * TD;        // kf
        float* f1 = f0 + FQ;            // vf (ctx in-place)
        float* f2 = f1 + FQ;            // qf

        gemm3_nt_bias<<<dim3(4, 64, 3), 256, 0, stream>>>(
            key, value, query, Wk, Wv, Wq, bk, bv, bq, t0, t1, t2);
        fft3_topk_mask<<<dim3(1024, 3), 256, 0, stream>>>(
            t0, t1, t2, f0, f1, f2);

        att_softmax_ctx<<<32 * 257, 64, 0, stream>>>(f2, f0, f1);
        irfft_residual<<<1024, 256, 0, stream>>>(f1, query, t0);
        layernorm_out<<<16384, 256, 0, stream>>>(t0, gamma, beta, out);
    } else {
        float* tdom = ws;
        float* freq = ws + TD;
        const float* Xs[3] = {key, value, query};
        const float* Wm[3] = {Wk, Wv, Wq};
        const float* Bs[3] = {bk, bv, bq};
        for (int t = 0; t < 3; ++t) {
            gemm3_nt_bias<<<dim3(4, 64, 1), 256, 0, stream>>>(
                Xs[t], Xs[t], Xs[t], Wm[t], Wm[t], Wm[t],
                Bs[t], Bs[t], Bs[t], tdom, tdom, tdom);
            fft3_topk_mask<<<dim3(1024, 1), 256, 0, stream>>>(
                tdom, tdom, tdom,
                freq + (size_t)t * FQ, freq + (size_t)t * FQ, freq + (size_t)t * FQ);
        }
        float* kfp = freq;
        float* vfp = freq + FQ;
        float* qfp = freq + 2 * FQ;
        att_softmax_ctx<<<32 * 257, 64, 0, stream>>>(qfp, kfp, vfp);
        irfft_residual<<<1024, 256, 0, stream>>>(vfp, query, tdom);
        layernorm_out<<<16384, 256, 0, stream>>>(tdom, gamma, beta, out);
    }
}